// Round 9
// baseline (73.561 us; speedup 1.0000x reference)
//
#include <hip/hip_runtime.h>

typedef float f2 __attribute__((ext_vector_type(2)));

#define HH 512
#define WW 512
#define NB 32
#define TW 64                    // output tile width (px)
#define TH 16                    // output tile height
#define RB 4                     // rows per thread (ty 0..3 -> rows 4ty..4ty+3)
#define NT 8                     // tiles per block (vertical walk)
#define TIW (TW + 4)             // 68 (halo P<=2 each side)
#define TIH (TH + 4)             // 20
#define NTILE (TIW * TIH)        // 1360
#define NSLOT 6                  // ceil(1360/256)
#define TAILT (NTILE - 256 * (NSLOT - 1))  // 80: slot5 valid for t<80
#define EPS 1e-5f

// Wave-uniform loads routed through constant address space -> s_load (SGPR).
__device__ __forceinline__ const __attribute__((address_space(4))) float*
cptr(const float* p) {
    return (const __attribute__((address_space(4))) float*)(unsigned long long)p;
}
__device__ __forceinline__ f2 ldw2(const float* p) {
    const __attribute__((address_space(4))) float* q = cptr(p);
    return f2{q[0], q[1]};
}
__device__ __forceinline__ float ldw1(const float* p) { return cptr(p)[0]; }

// packed math: llvm.fma.v2f32 -> v_pk_fma_f32 (VOP3P).
__device__ __forceinline__ f2 pkfma(f2 a, f2 b, f2 c) {
    return __builtin_elementwise_fma(a, b, c);
}
__device__ __forceinline__ f2 splat(float v) { return f2{v, v}; }

__device__ __forceinline__ float4 ldx4(const float* __restrict__ x, int b, int h, int w) {
    return *reinterpret_cast<const float4*>(x + ((((size_t)b * HH + h) * WW + w) << 2));
}

// issue the 6-slot register prefetch for tile at row h0 (fast path: pointer+offset)
__device__ __forceinline__ void load_pf_fast(const float* __restrict__ pbase,
                                             const int* goff, int t, float4 pf[NSLOT]) {
#pragma unroll
    for (int j = 0; j < NSLOT; ++j) {
        if (j == NSLOT - 1 && t >= TAILT) continue;
        pf[j] = *reinterpret_cast<const float4*>(pbase + goff[j]);
    }
}

__device__ __forceinline__ void load_pf_chk(const float* __restrict__ x, int b, int h0,
                                            int w0p, const int* tr, const int* tc,
                                            int t, float4 pf[NSLOT]) {
#pragma unroll
    for (int j = 0; j < NSLOT; ++j) {
        if (j == NSLOT - 1 && t >= TAILT) continue;
        int gr = h0 - 2 + tr[j];
        int gc = w0p - 2 + tc[j];
        float4 v = {0.f, 0.f, 0.f, 0.f};
        if (((unsigned)gr < (unsigned)HH) & ((unsigned)gc < (unsigned)WW))
            v = ldx4(x, b, gr, gc);
        pf[j] = v;
    }
}

// compute RB vertical output px from the staged tile; weights HWIO (SGPR loads)
template <int K, bool DW>
__device__ __forceinline__ void conv_tile(const float4* __restrict__ tile,  // [TIH][TIW]
                                          const float* __restrict__ wgt,
                                          int tx, int ty,
                                          f2 accl[RB], f2 acch[RB]) {
    constexpr int P = K / 2;
#pragma unroll
    for (int i = 0; i < RB + 2 * P; ++i) {
        const float4* trow = tile + (ty * RB + (2 - P) + i) * TIW + tx + (2 - P);
        float4 win[K];
#pragma unroll
        for (int kj = 0; kj < K; ++kj) win[kj] = trow[kj];
#pragma unroll
        for (int r = 0; r < RB; ++r) {
            int ki = i - r;                       // compile-time per (i,r)
            if (ki < 0 || ki >= K) continue;
#pragma unroll
            for (int kj = 0; kj < K; ++kj) {
                float4 p = win[kj];
                if (DW) {
                    const float* wp = wgt + (ki * K + kj) * 4;   // [c]
                    accl[r] = pkfma(f2{p.x, p.y}, ldw2(wp + 0), accl[r]);
                    acch[r] = pkfma(f2{p.z, p.w}, ldw2(wp + 2), acch[r]);
                } else {
                    const float* wp = wgt + (ki * K + kj) * 16;  // [in][out] 4x4
                    f2 px = splat(p.x), py = splat(p.y);
                    f2 pz = splat(p.z), pw = splat(p.w);
                    accl[r] = pkfma(px, ldw2(wp + 0),  accl[r]);
                    accl[r] = pkfma(py, ldw2(wp + 4),  accl[r]);
                    accl[r] = pkfma(pz, ldw2(wp + 8),  accl[r]);
                    accl[r] = pkfma(pw, ldw2(wp + 12), accl[r]);
                    acch[r] = pkfma(px, ldw2(wp + 2),  acch[r]);
                    acch[r] = pkfma(py, ldw2(wp + 6),  acch[r]);
                    acch[r] = pkfma(pz, ldw2(wp + 10), acch[r]);
                    acch[r] = pkfma(pw, ldw2(wp + 14), acch[r]);
                }
            }
        }
    }
}

struct BN { f2 ivl, ivh, shl, shh; };

__device__ __forceinline__ BN make_bn(const float* gamma, const float* beta,
                                      const float* mean, const float* var, int idx) {
    const float* ga = gamma + idx * 4;
    const float* be = beta + idx * 4;
    const float* mu = mean + idx * 4;
    const float* vr = var + idx * 4;
    f2 g01 = ldw2(ga + 0), g23 = ldw2(ga + 2);
    f2 v01 = ldw2(vr + 0), v23 = ldw2(vr + 2);
    f2 b01 = ldw2(be + 0), b23 = ldw2(be + 2);
    f2 m01 = ldw2(mu + 0), m23 = ldw2(mu + 2);
    BN bn;
    bn.ivl = f2{g01.x * rsqrtf(v01.x + EPS), g01.y * rsqrtf(v01.y + EPS)};
    bn.ivh = f2{g23.x * rsqrtf(v23.x + EPS), g23.y * rsqrtf(v23.y + EPS)};
    bn.shl = b01 - m01 * bn.ivl;
    bn.shh = b23 - m23 * bn.ivh;
    return bn;
}

__device__ __forceinline__ void bn_store(float* __restrict__ out, const BN& bn,
                                         const f2 accl[RB], const f2 acch[RB],
                                         int b, int h0, int ty, int w0p, int tx) {
#pragma unroll
    for (int r = 0; r < RB; ++r) {
        f2 ol = pkfma(accl[r], bn.ivl, bn.shl);
        f2 oh = pkfma(acch[r], bn.ivh, bn.shh);
        float4 o;
        o.x = ol.x > 0.f ? ol.x : 0.f;
        o.y = ol.y > 0.f ? ol.y : 0.f;
        o.z = oh.x > 0.f ? oh.x : 0.f;
        o.w = oh.y > 0.f ? oh.y : 0.f;
        *reinterpret_cast<float4*>(
            out + ((((size_t)b * HH + h0 + ty * RB + r) * WW + w0p + tx) << 2)) = o;
    }
}

// pipelined multi-tile loop: ds_write(i) -> barrier -> issue loads(i+1) ->
// compute(i) -> store -> barrier.  pf must stay register-resident: needs
// the 128-VGPR budget from __launch_bounds__(256,2).
template <int K, bool DW>
__device__ __forceinline__ void run_tiles(const float* __restrict__ x,
                                          float* __restrict__ out,
                                          const float* __restrict__ wgt,
                                          const BN& bn, float4* tile,
                                          int b, int h0b, int w0p,
                                          const int* tr, const int* tc,
                                          const int* goff, int t, int tx, int ty,
                                          bool wchk) {
    // per-thread base pointer for fast staging: &x[b][h0b-2+tr][w0p-2+tc]
    const float* pbase = x + (((size_t)b * HH + (h0b - 2)) * WW + (w0p - 2)) * 4;
    float4 pf[NSLOT];
    if (wchk) load_pf_chk(x, b, h0b, w0p, tr, tc, t, pf);   // h0b==0 row OOB too
    else      load_pf_chk(x, b, h0b, w0p, tr, tc, t, pf);   // first tile always checked (top halo)
#pragma unroll 1
    for (int i = 0; i < NT; ++i) {
        int h0 = h0b + i * TH;
#pragma unroll
        for (int j = 0; j < NSLOT; ++j) {
            if (j == NSLOT - 1 && t >= TAILT) continue;
            tile[t + 256 * j] = pf[j];
        }
        __syncthreads();
        if (i + 1 < NT) {
            int h1 = h0 + TH;
            bool chk = wchk | (h1 + TIH - 3 >= HH);   // bottom rows OOB on last tiles
            if (chk) load_pf_chk(x, b, h1, w0p, tr, tc, t, pf);
            else     load_pf_fast(pbase + (size_t)(i + 1) * TH * WW * 4, goff, t, pf);
        }
        f2 accl[RB] = {f2{0.f,0.f}, f2{0.f,0.f}, f2{0.f,0.f}, f2{0.f,0.f}};
        f2 acch[RB] = {f2{0.f,0.f}, f2{0.f,0.f}, f2{0.f,0.f}, f2{0.f,0.f}};
        conv_tile<K, DW>(tile, wgt, tx, ty, accl, acch);
        bn_store(out, bn, accl, acch, b, h0, ty, w0p, tx);
        __syncthreads();
    }
}

__global__ __launch_bounds__(256, 2) void mixop_kernel(
    const float* __restrict__ x,
    const float* __restrict__ logits, const float* __restrict__ g,
    const float* __restrict__ w0, const float* __restrict__ w1,
    const float* __restrict__ w2, const float* __restrict__ w3,
    const float* __restrict__ w4,
    const float* __restrict__ gamma, const float* __restrict__ beta,
    const float* __restrict__ mean, const float* __restrict__ var,
    float* __restrict__ out) {
    __shared__ float4 tile[NTILE];

    int t   = threadIdx.x;
    int blk = blockIdx.x;
    int bw  = blk & 7;             // WW/TW = 8
    int hg  = (blk >> 3) & 3;      // HH/(TH*NT) = 4
    int b   = blk >> 5;            // batch
    int w0p = bw * TW;
    int h0b = hg * (TH * NT);
    bool wchk = (bw == 0) | (bw == 7);

    // wave-uniform routing: argmax(logits + g), first-max wins (s_load inputs)
    int idx = 0;
    float best = ldw1(logits + 0) + ldw1(g + 0);
#pragma unroll
    for (int i = 1; i < 5; ++i) {
        float v = ldw1(logits + i) + ldw1(g + i);
        if (v > best) { best = v; idx = i; }
    }

    int tx = t & 63;               // lane-consecutive w -> coalesced I/O
    int ty = t >> 6;

    BN bn = make_bn(gamma, beta, mean, var, idx);

    if (idx == 0) {
        // 1x1 conv: no reuse -> direct global reads, no LDS/barriers
        f2 a0 = ldw2(w0 + 0),  c0 = ldw2(w0 + 2);
        f2 a1 = ldw2(w0 + 4),  c1 = ldw2(w0 + 6);
        f2 a2 = ldw2(w0 + 8),  c2 = ldw2(w0 + 10);
        f2 a3 = ldw2(w0 + 12), c3 = ldw2(w0 + 14);
#pragma unroll 1
        for (int i = 0; i < NT; ++i) {
            int h0 = h0b + i * TH;
            f2 accl[RB], acch[RB];
#pragma unroll
            for (int r = 0; r < RB; ++r) {
                float4 p = ldx4(x, b, h0 + ty * RB + r, w0p + tx);
                f2 px = splat(p.x), py = splat(p.y);
                f2 pz = splat(p.z), pw = splat(p.w);
                accl[r] = px * a0;
                accl[r] = pkfma(py, a1, accl[r]);
                accl[r] = pkfma(pz, a2, accl[r]);
                accl[r] = pkfma(pw, a3, accl[r]);
                acch[r] = px * c0;
                acch[r] = pkfma(py, c1, acch[r]);
                acch[r] = pkfma(pz, c2, acch[r]);
                acch[r] = pkfma(pw, c3, acch[r]);
            }
            bn_store(out, bn, accl, acch, b, h0, ty, w0p, tx);
        }
        return;
    }

    // per-thread staging coords + float offsets, computed once per block
    int tr[NSLOT], tc[NSLOT], goff[NSLOT];
#pragma unroll
    for (int j = 0; j < NSLOT; ++j) {
        int k = t + 256 * j;
        tr[j] = k / TIW;
        tc[j] = k - tr[j] * TIW;
        goff[j] = (tr[j] * WW + tc[j]) * 4;
    }

    switch (idx) {
        case 1: run_tiles<3, false>(x, out, w1, bn, tile, b, h0b, w0p, tr, tc, goff, t, tx, ty, wchk); break;
        case 2: run_tiles<3, true >(x, out, w2, bn, tile, b, h0b, w0p, tr, tc, goff, t, tx, ty, wchk); break;
        case 3: run_tiles<5, false>(x, out, w3, bn, tile, b, h0b, w0p, tr, tc, goff, t, tx, ty, wchk); break;
        case 4: run_tiles<5, true >(x, out, w4, bn, tile, b, h0b, w0p, tr, tc, goff, t, tx, ty, wchk); break;
    }
}

extern "C" void kernel_launch(void* const* d_in, const int* in_sizes, int n_in,
                              void* d_out, int out_size, void* d_ws, size_t ws_size,
                              hipStream_t stream) {
    const float* x      = (const float*)d_in[0];
    const float* logits = (const float*)d_in[1];
    const float* g      = (const float*)d_in[2];
    const float* w0     = (const float*)d_in[3];
    const float* w1     = (const float*)d_in[4];
    const float* w2     = (const float*)d_in[5];
    const float* w3     = (const float*)d_in[6];
    const float* w4     = (const float*)d_in[7];
    const float* gamma  = (const float*)d_in[8];
    const float* beta   = (const float*)d_in[9];
    const float* mean   = (const float*)d_in[10];
    const float* var    = (const float*)d_in[11];
    float* out = (float*)d_out;

    const int blocks = NB * (WW / TW) * (HH / (TH * NT));  // 32*8*4 = 1024
    mixop_kernel<<<blocks, 256, 0, stream>>>(
        x, logits, g, w0, w1, w2, w3, w4, gamma, beta, mean, var, out);
}

// Round 10
// 50.667 us; speedup vs baseline: 1.4518x; 1.4518x over previous
//
#include <hip/hip_runtime.h>

typedef float f2 __attribute__((ext_vector_type(2)));
typedef float f32x4 __attribute__((ext_vector_type(4)));
typedef short bf16x8 __attribute__((ext_vector_type(8)));

#define HH 512
#define WW 512
#define NB 32
#define BT 64                 // block tile: 64x64 output px
#define TIH 68                // staged input rows  (r0-2 .. r0+65)
#define TIWP 68               // staged px per row  (c0-2 .. c0+65)
#define ROWB 560              // LDS row stride bytes (70 px * 8B, bank-padded)
#define EPS 1e-5f

// Wave-uniform loads via constant address space -> s_load.
__device__ __forceinline__ const __attribute__((address_space(4))) float*
cptr(const float* p) {
    return (const __attribute__((address_space(4))) float*)(unsigned long long)p;
}
__device__ __forceinline__ float ldw1(const float* p) { return cptr(p)[0]; }

__device__ __forceinline__ unsigned short f2bf(float f) {  // RNE float->bf16
    unsigned u = __float_as_uint(f);
    unsigned r = (u + 0x7FFFu + ((u >> 16) & 1u)) >> 16;
    return (unsigned short)r;
}

__device__ __forceinline__ float4 ldx4(const float* __restrict__ x, int b, int h, int w) {
    return *reinterpret_cast<const float4*>(x + ((((size_t)b * HH + h) * WW + w) << 2));
}

struct BNs { float iv[4], sh[4]; };

__device__ __forceinline__ BNs make_bns(const float* gamma, const float* beta,
                                        const float* mean, const float* var, int idx) {
    BNs bn;
#pragma unroll
    for (int c = 0; c < 4; ++c) {
        float iv = ldw1(gamma + idx * 4 + c) * rsqrtf(ldw1(var + idx * 4 + c) + EPS);
        bn.iv[c] = iv;
        bn.sh[c] = ldw1(beta + idx * 4 + c) - ldw1(mean + idx * 4 + c) * iv;
    }
    return bn;
}

// ---------------- MFMA path: full KxK conv (4->4 ch) via shifted-B implicit GEMM.
// One mfma_f32_16x16x32_bf16: M=16 output rows, N=16=(4 shifts x 4 oc),
// K=32=(8 px cols x 4 ic).  B[k=(j,ic)][n=(s,oc)] = w[ki][j-s-(2-P)][ic][oc] or 0.
// Accumulate over ki (K MFMAs).  A rows stream from the bf16 LDS tile.
template <int K>
__device__ __forceinline__ void conv_mfma(const float* __restrict__ x,
                                          float* __restrict__ out,
                                          const float* __restrict__ wgt,
                                          const float* __restrict__ gamma,
                                          const float* __restrict__ beta,
                                          const float* __restrict__ mean,
                                          const float* __restrict__ var, int idx,
                                          char* lds, int b, int r0, int c0, int t) {
    const int l  = t & 63, wv = t >> 6;
    const int n  = l & 15, kc = l >> 4;      // n = MFMA col, kc = k-chunk
    const int s  = n >> 2, oc = n & 3;       // col -> (shift, out-channel)
    constexpr int OFF = 2 - K / 2;           // row/col offset into the +-2 halo

    // B fragments, lane-resident (built once; divergent small reads)
    bf16x8 Bf[K];
#pragma unroll
    for (int ki = 0; ki < K; ++ki) {
#pragma unroll
        for (int e = 0; e < 8; ++e) {
            int k = kc * 8 + e;
            int j = k >> 2, ic = k & 3;
            int jj = j - s - OFF;
            float v = (jj >= 0 && jj < K) ? wgt[((ki * K + jj) * 4 + ic) * 4 + oc] : 0.f;
            Bf[ki][e] = (short)f2bf(v);
        }
    }

    // per-lane BN constants for this lane's fixed output channel
    float iv = gamma[idx * 4 + oc] * rsqrtf(var[idx * 4 + oc] + EPS);
    float sh = beta[idx * 4 + oc] - mean[idx * 4 + oc] * iv;

    // stage 68x68 px as packed bf16x4 (8B/px), zero-filled SAME halo
    for (int kk = t; kk < TIH * TIWP; kk += 256) {
        int row = kk / TIWP;
        int tc  = kk - row * TIWP;
        int gr  = r0 - 2 + row;
        int gc  = c0 - 2 + tc;
        uint2 v = {0u, 0u};
        if (((unsigned)gr < (unsigned)HH) & ((unsigned)gc < (unsigned)WW)) {
            float4 p = ldx4(x, b, gr, gc);
            v.x = (unsigned)f2bf(p.x) | ((unsigned)f2bf(p.y) << 16);
            v.y = (unsigned)f2bf(p.z) | ((unsigned)f2bf(p.w) << 16);
        }
        *reinterpret_cast<uint2*>(lds + row * ROWB + tc * 8) = v;
    }
    __syncthreads();

    // A row base for this lane: tile row = 16*wave + (l&15) + OFF + ki
    const int rbase = 16 * wv + (l & 15) + OFF;
    // D lane mapping: row m = kc*4 + r, col n -> (s, oc)
    size_t obase = (((size_t)b * HH + r0 + 16 * wv + kc * 4) * WW + c0 + s) * 4 + oc;

#pragma unroll 2
    for (int j0 = 0; j0 < 16; ++j0) {        // 4-col output groups across 64 px
        f32x4 acc = {0.f, 0.f, 0.f, 0.f};
#pragma unroll
        for (int ki = 0; ki < K; ++ki) {
            bf16x8 a = *reinterpret_cast<const bf16x8*>(
                lds + (rbase + ki) * ROWB + kc * 16 + j0 * 32);
            acc = __builtin_amdgcn_mfma_f32_16x16x32_bf16(a, Bf[ki], acc, 0, 0, 0);
        }
#pragma unroll
        for (int r = 0; r < 4; ++r) {
            float v = acc[r] * iv + sh;
            v = v > 0.f ? v : 0.f;
            out[obase + (size_t)r * (WW * 4) + j0 * 16] = v;
        }
    }
}

// ---------------- cold fallbacks (never selected with this input; correctness only)
template <int K>
__device__ void conv_dw_naive(const float* __restrict__ x, float* __restrict__ out,
                              const float* __restrict__ wgt, const BNs& bn,
                              int b, int r0, int c0, int t) {
    int col = c0 + (t & 63);
    int rb  = r0 + (t >> 6) * 16;
    for (int rr = 0; rr < 16; ++rr) {
        int orow = rb + rr;
        float a0 = 0.f, a1 = 0.f, a2 = 0.f, a3 = 0.f;
#pragma unroll
        for (int ki = 0; ki < K; ++ki) {
            int gr = orow + ki - K / 2;
            if ((unsigned)gr >= (unsigned)HH) continue;
#pragma unroll
            for (int kj = 0; kj < K; ++kj) {
                int gc = col + kj - K / 2;
                if ((unsigned)gc >= (unsigned)WW) continue;
                float4 p = ldx4(x, b, gr, gc);
                const float* wp = wgt + (ki * K + kj) * 4;
                a0 += p.x * wp[0]; a1 += p.y * wp[1];
                a2 += p.z * wp[2]; a3 += p.w * wp[3];
            }
        }
        float4 o;
        o.x = fmaxf(a0 * bn.iv[0] + bn.sh[0], 0.f);
        o.y = fmaxf(a1 * bn.iv[1] + bn.sh[1], 0.f);
        o.z = fmaxf(a2 * bn.iv[2] + bn.sh[2], 0.f);
        o.w = fmaxf(a3 * bn.iv[3] + bn.sh[3], 0.f);
        *reinterpret_cast<float4*>(out + ((((size_t)b * HH + orow) * WW + col) << 2)) = o;
    }
}

__device__ void conv_1x1(const float* __restrict__ x, float* __restrict__ out,
                         const float* __restrict__ w0, const BNs& bn,
                         int b, int r0, int c0, int t) {
    int col = c0 + (t & 63);
    int rb  = r0 + (t >> 6) * 16;
    for (int rr = 0; rr < 16; ++rr) {
        float4 p = ldx4(x, b, rb + rr, col);
        float4 o;
        float a0 = p.x * ldw1(w0 + 0) + p.y * ldw1(w0 + 4) + p.z * ldw1(w0 + 8)  + p.w * ldw1(w0 + 12);
        float a1 = p.x * ldw1(w0 + 1) + p.y * ldw1(w0 + 5) + p.z * ldw1(w0 + 9)  + p.w * ldw1(w0 + 13);
        float a2 = p.x * ldw1(w0 + 2) + p.y * ldw1(w0 + 6) + p.z * ldw1(w0 + 10) + p.w * ldw1(w0 + 14);
        float a3 = p.x * ldw1(w0 + 3) + p.y * ldw1(w0 + 7) + p.z * ldw1(w0 + 11) + p.w * ldw1(w0 + 15);
        o.x = fmaxf(a0 * bn.iv[0] + bn.sh[0], 0.f);
        o.y = fmaxf(a1 * bn.iv[1] + bn.sh[1], 0.f);
        o.z = fmaxf(a2 * bn.iv[2] + bn.sh[2], 0.f);
        o.w = fmaxf(a3 * bn.iv[3] + bn.sh[3], 0.f);
        *reinterpret_cast<float4*>(out + ((((size_t)b * HH + rb + rr) * WW + col) << 2)) = o;
    }
}

__global__ __launch_bounds__(256, 4) void mixop_kernel(
    const float* __restrict__ x,
    const float* __restrict__ logits, const float* __restrict__ g,
    const float* __restrict__ w0, const float* __restrict__ w1,
    const float* __restrict__ w2, const float* __restrict__ w3,
    const float* __restrict__ w4,
    const float* __restrict__ gamma, const float* __restrict__ beta,
    const float* __restrict__ mean, const float* __restrict__ var,
    float* __restrict__ out) {
    __shared__ __align__(16) char lds[TIH * ROWB];   // 38 KB bf16 tile

    int t   = threadIdx.x;
    int blk = blockIdx.x;
    int bw  = blk & 7;             // 512/64 = 8 col tiles
    int bh  = (blk >> 3) & 7;      // 8 row tiles
    int b   = blk >> 6;            // batch
    int c0  = bw * BT;
    int r0  = bh * BT;

    // wave-uniform routing: argmax(logits + g), first-max wins
    int idx = 0;
    float best = ldw1(logits + 0) + ldw1(g + 0);
#pragma unroll
    for (int i = 1; i < 5; ++i) {
        float v = ldw1(logits + i) + ldw1(g + i);
        if (v > best) { best = v; idx = i; }
    }

    switch (idx) {
        case 0: { BNs bn = make_bns(gamma, beta, mean, var, 0);
                  conv_1x1(x, out, w0, bn, b, r0, c0, t); break; }
        case 1: conv_mfma<3>(x, out, w1, gamma, beta, mean, var, 1, lds, b, r0, c0, t); break;
        case 2: { BNs bn = make_bns(gamma, beta, mean, var, 2);
                  conv_dw_naive<3>(x, out, w2, bn, b, r0, c0, t); break; }
        case 3: conv_mfma<5>(x, out, w3, gamma, beta, mean, var, 3, lds, b, r0, c0, t); break;
        case 4: { BNs bn = make_bns(gamma, beta, mean, var, 4);
                  conv_dw_naive<5>(x, out, w4, bn, b, r0, c0, t); break; }
    }
}

extern "C" void kernel_launch(void* const* d_in, const int* in_sizes, int n_in,
                              void* d_out, int out_size, void* d_ws, size_t ws_size,
                              hipStream_t stream) {
    const float* x      = (const float*)d_in[0];
    const float* logits = (const float*)d_in[1];
    const float* g      = (const float*)d_in[2];
    const float* w0     = (const float*)d_in[3];
    const float* w1     = (const float*)d_in[4];
    const float* w2     = (const float*)d_in[5];
    const float* w3     = (const float*)d_in[6];
    const float* w4     = (const float*)d_in[7];
    const float* gamma  = (const float*)d_in[8];
    const float* beta   = (const float*)d_in[9];
    const float* mean   = (const float*)d_in[10];
    const float* var    = (const float*)d_in[11];
    float* out = (float*)d_out;

    const int blocks = NB * 8 * 8;   // 2048 tiles of 64x64
    mixop_kernel<<<blocks, 256, 0, stream>>>(
        x, logits, g, w0, w1, w2, w3, w4, gamma, beta, mean, var, out);
}